// Round 1
// 186.726 us; speedup vs baseline: 1.0176x; 1.0176x over previous
//
#include <hip/hip_runtime.h>

// Problem constants: B=2, S=4096, H=8, DH=64, D=512, M = B*S = 8192.
#define LOG2E 1.44269504088896340736f

typedef unsigned short u16;
typedef __bf16 bf16x4_t __attribute__((ext_vector_type(4)));
typedef __bf16 bf16x8_t __attribute__((ext_vector_type(8)));
typedef float f32x4_t __attribute__((ext_vector_type(4)));

__device__ __forceinline__ f32x4_t mfma16(bf16x8_t a, bf16x8_t b, f32x4_t c) {
  return __builtin_amdgcn_mfma_f32_16x16x32_bf16(a, b, c, 0, 0, 0);
}

// async 16B global -> LDS (dest = wave-uniform base + lane*16)
__device__ __forceinline__ void gl_lds16(const u16* g, u16* l) {
  __builtin_amdgcn_global_load_lds(
      (const __attribute__((address_space(1))) unsigned int*)g,
      (__attribute__((address_space(3))) unsigned int*)l, 16, 0, 0);
}

// ---------------- one-shot cast: fp32 -> bf16 (Wq pre-scaled by 0.125*log2e) --------------
// regions: blocks [0,2048) = X (4.19M elems), then 128 blocks each for Wq,Wk,Wv,Wo (256K).
__global__ __launch_bounds__(256) void cast_kernel(
    const float* __restrict__ x, const float* __restrict__ Wq, const float* __restrict__ Wk,
    const float* __restrict__ Wv, const float* __restrict__ Wo,
    u16* __restrict__ Xb, u16* __restrict__ Wqb, u16* __restrict__ Wkb,
    u16* __restrict__ Wvb, u16* __restrict__ Wob) {
  const int bid = blockIdx.x;
  const float* src;
  u16* dst;
  float scale = 1.f;
  int rel;
  if (bid < 2048)      { src = x;  dst = Xb;  rel = bid; }
  else if (bid < 2176) { src = Wq; dst = Wqb; rel = bid - 2048; scale = 0.125f * LOG2E; }
  else if (bid < 2304) { src = Wk; dst = Wkb; rel = bid - 2176; }
  else if (bid < 2432) { src = Wv; dst = Wvb; rel = bid - 2304; }
  else                 { src = Wo; dst = Wob; rel = bid - 2432; }
  const int i = rel * 2048 + threadIdx.x * 8;
  f32x4_t a = *(const f32x4_t*)(src + i) * scale;
  f32x4_t b = *(const f32x4_t*)(src + i + 4) * scale;
  union { uint4 u; struct { bf16x4_t lo, hi; } s; } c;
  c.s.lo = __builtin_convertvector(a, bf16x4_t);
  c.s.hi = __builtin_convertvector(b, bf16x4_t);
  *(uint4*)(dst + i) = c.u;
}

// ---------------- bf16 GEMM core (m97 structure): C = A[*,512] @ Bt[*,512]^T --------------
// 128x128 tile, BK=64, single-buffered 32KB LDS, global_load_lds width=16.
// LDS swizzle: LDS[row][slot] holds G[row][slot ^ (row&7)] (slot = 16B unit, 8 per row).
// Achieved by pre-swizzling the per-lane GLOBAL source address (linear LDS dest, rule #21)
// and XOR-ing the same pattern on the ds_read_b128 side -> conflict-free (2-way only).
// MODE 0: bf16 row-major C (stride 512). MODE 1: V^T scatter. MODE 2: f32 + bias.
template <int MODE>
__device__ __forceinline__ void gemm_core_bf16(const u16* __restrict__ A, const u16* __restrict__ Bt,
                                               void* __restrict__ Cout, const float* __restrict__ bo,
                                               int Mbase, int Nbase) {
  __shared__ __align__(16) u16 As[128][64];
  __shared__ __align__(16) u16 Bs[128][64];
  const int t = threadIdx.x;
  const int wave = t >> 6, lane = t & 63;
  const int r = lane & 15, qd = lane >> 4;
  const int wm = wave & 1, wn = wave >> 1;
  // staging: lane covers (row-in-group = lane>>3, lds slot = lane&7); global slot pre-swizzled
  const int rr = lane >> 3;
  const int s8 = ((lane & 7) ^ (rr & 7)) * 8;

  f32x4_t acc[4][4];
#pragma unroll
  for (int i = 0; i < 4; i++)
#pragma unroll
    for (int j = 0; j < 4; j++) { f32x4_t z = {0.f, 0.f, 0.f, 0.f}; acc[i][j] = z; }

  const u16* pa = A  + (Mbase + wave * 32 + rr) * 512 + s8;
  const u16* pb = Bt + (Nbase + wave * 32 + rr) * 512 + s8;
  u16* la = &As[wave * 32][0];
  u16* lb = &Bs[wave * 32][0];

  for (int k0 = 0; k0 < 512; k0 += 64) {
#pragma unroll
    for (int j = 0; j < 4; j++) gl_lds16(pa + k0 + j * 8 * 512, la + j * 8 * 64);
#pragma unroll
    for (int j = 0; j < 4; j++) gl_lds16(pb + k0 + j * 8 * 512, lb + j * 8 * 64);
    __syncthreads();  // compiler drains vmcnt(0) here (m97 structure)
#pragma unroll
    for (int h = 0; h < 2; h++) {
      bf16x8_t af[4], bfr[4];
#pragma unroll
      for (int i = 0; i < 4; i++)
        af[i]  = *(const bf16x8_t*)&As[wm * 64 + i * 16 + r][((h * 4 + qd) ^ (r & 7)) * 8];
#pragma unroll
      for (int j = 0; j < 4; j++)
        bfr[j] = *(const bf16x8_t*)&Bs[wn * 64 + j * 16 + r][((h * 4 + qd) ^ (r & 7)) * 8];
#pragma unroll
      for (int i = 0; i < 4; i++)
#pragma unroll
        for (int j = 0; j < 4; j++) acc[i][j] = mfma16(af[i], bfr[j], acc[i][j]);
    }
    __syncthreads();
  }

  float bv[4];
  if (MODE == 2) {
#pragma unroll
    for (int j = 0; j < 4; j++) bv[j] = bo[Nbase + wn * 64 + j * 16 + r];
  }
#pragma unroll
  for (int i = 0; i < 4; i++) {
#pragma unroll
    for (int reg = 0; reg < 4; reg++) {
      int gr = Mbase + wm * 64 + i * 16 + qd * 4 + reg;
#pragma unroll
      for (int j = 0; j < 4; j++) {
        int gc = Nbase + wn * 64 + j * 16 + r;
        float val = acc[i][j][reg];
        if (MODE == 1) {
          int bb = gc >> 12, ss = gc & 4095;
          ((__bf16*)Cout)[((long)(bb * 512 + gr)) * 4096 + ss] = (__bf16)val;
        } else if (MODE == 0) {
          ((__bf16*)Cout)[gr * 512 + gc] = (__bf16)val;
        } else {
          ((float*)Cout)[gr * 512 + gc] = val + bv[j];
        }
      }
    }
  }
}

__global__ __launch_bounds__(256) void gemm_qkv_kernel(
    const u16* __restrict__ Xb,
    const u16* __restrict__ Wqb, const u16* __restrict__ Wkb, const u16* __restrict__ Wvb,
    u16* __restrict__ Q, u16* __restrict__ K, u16* __restrict__ Vt) {
  if (blockIdx.z == 0)
    gemm_core_bf16<0>(Xb, Wqb, Q, nullptr, blockIdx.x * 128, blockIdx.y * 128);
  else if (blockIdx.z == 1)
    gemm_core_bf16<0>(Xb, Wkb, K, nullptr, blockIdx.x * 128, blockIdx.y * 128);
  else  // V^T = Wv @ X^T
    gemm_core_bf16<1>(Wvb, Xb, Vt, nullptr, blockIdx.y * 128, blockIdx.x * 128);
}

__global__ __launch_bounds__(256) void gemm_out_kernel(
    const u16* __restrict__ Aat, const u16* __restrict__ Wob,
    float* __restrict__ Out, const float* __restrict__ bo) {
  gemm_core_bf16<2>(Aat, Wob, Out, bo, blockIdx.x * 128, blockIdx.y * 128);
}

// ---------------- flash attention v7 (+ s_setprio around MFMA clusters) -------------------
__global__ __launch_bounds__(256, 2) void attn_kernel(
    const u16* __restrict__ Q, const u16* __restrict__ K, const u16* __restrict__ Vt,
    u16* __restrict__ Oattn) {
  __shared__ __align__(16) u16 Ks[2][2][4096];
  __shared__ __align__(16) u16 Vs[2][2][4096];

  const int t = threadIdx.x;
  const int wave = t >> 6, lane = t & 63;
  const int r = lane & 15, qd = lane >> 4;
  const int g = wave & 1, kv = wave >> 1;
  const int bh = blockIdx.y;
  const int b = bh >> 3, h = bh & 7;
  const long bbase = (long)b * 4096 * 512;
  const int q0 = blockIdx.x * 128;

  const int sw = r & 7;
  const int ck0 = (qd ^ sw) * 8;
  const int ck1 = ((qd + 4) ^ sw) * 8;
  int vo0[2], vo1[2];
#pragma unroll
  for (int c = 0; c < 2; c++) {
    vo0[c] = ((c * 4 + (qd >> 1)) ^ sw) * 8 + 4 * (qd & 1);
    vo1[c] = ((c * 4 + 2 + (qd >> 1)) ^ sw) * 8 + 4 * (qd & 1);
  }

  bf16x8_t ones8;
#pragma unroll
  for (int j = 0; j < 8; j++) ones8[j] = (__bf16)1.0f;

  bf16x8_t qf[4][2];
#pragma unroll
  for (int qa = 0; qa < 4; qa++) {
    const u16* qp = Q + bbase + (long)(q0 + g * 64 + qa * 16 + r) * 512 + h * 64 + qd * 8;
    qf[qa][0] = *(const bf16x8_t*)(qp);
    qf[qa][1] = *(const bf16x8_t*)(qp + 32);
  }

  f32x4_t accO[4][4];
  f32x4_t accL[4];
#pragma unroll
  for (int qa = 0; qa < 4; qa++) {
    f32x4_t z = {0.f, 0.f, 0.f, 0.f};
    accL[qa] = z;
#pragma unroll
    for (int nt = 0; nt < 4; nt++) accO[qa][nt] = z;
  }

  const int rr = lane >> 3;
  const int cc = (lane & 7) ^ rr;
  const u16* kgb = K + bbase + (long)(kv * 2048 + g * 32 + rr) * 512 + h * 64 + cc * 8;
  const u16* vgb = Vt + ((long)(b * 512 + h * 64 + g * 32 + rr)) * 4096 + kv * 2048 + cc * 8;

#pragma unroll
  for (int i = 0; i < 4; i++) gl_lds16(kgb + (long)i * 8 * 512, &Ks[kv][0][g * 2048] + i * 512);
#pragma unroll
  for (int i = 0; i < 4; i++) gl_lds16(vgb + i * 8 * 4096, &Vs[kv][0][g * 2048] + i * 512);

  for (int it = 0; it < 32; it++) {
    const int buf = it & 1;
    __syncthreads();

    if (it < 31) {
      const int nb = (it + 1) & 1;
      const long ko = (long)(it + 1) * 64;
#pragma unroll
      for (int i = 0; i < 4; i++)
        gl_lds16(kgb + (ko + i * 8) * 512, &Ks[kv][nb][g * 2048] + i * 512);
#pragma unroll
      for (int i = 0; i < 4; i++)
        gl_lds16(vgb + ko + (long)i * 8 * 4096, &Vs[kv][nb][g * 2048] + i * 512);
    }

    bf16x8_t kf[4][2];
#pragma unroll
    for (int nt = 0; nt < 4; nt++) {
      const u16* kb = &Ks[kv][buf][(nt * 16 + r) * 64];
      kf[nt][0] = *(const bf16x8_t*)(kb + ck0);
      kf[nt][1] = *(const bf16x8_t*)(kb + ck1);
    }

    f32x4_t St[4][4];
    __builtin_amdgcn_s_setprio(1);
#pragma unroll
    for (int qa = 0; qa < 4; qa++)
#pragma unroll
      for (int nt = 0; nt < 4; nt++) {
        f32x4_t z = {0.f, 0.f, 0.f, 0.f};
        z = mfma16(kf[nt][0], qf[qa][0], z);
        z = mfma16(kf[nt][1], qf[qa][1], z);
        St[qa][nt] = z;
      }
    __builtin_amdgcn_s_setprio(0);

    bf16x8_t pf[4][2];
#pragma unroll
    for (int qa = 0; qa < 4; qa++)
#pragma unroll
      for (int c = 0; c < 2; c++) {
        f32x4_t e0, e1;
#pragma unroll
        for (int j = 0; j < 4; j++) {
          e0[j] = __builtin_amdgcn_exp2f(St[qa][2 * c][j]);
          e1[j] = __builtin_amdgcn_exp2f(St[qa][2 * c + 1][j]);
        }
        bf16x4_t b0 = __builtin_convertvector(e0, bf16x4_t);
        bf16x4_t b1 = __builtin_convertvector(e1, bf16x4_t);
        bf16x8_t p8;
#pragma unroll
        for (int j = 0; j < 4; j++) { p8[j] = b0[j]; p8[4 + j] = b1[j]; }
        pf[qa][c] = p8;
      }

#pragma unroll
    for (int qa = 0; qa < 4; qa++)
#pragma unroll
      for (int c = 0; c < 2; c++)
        accL[qa] = mfma16(ones8, pf[qa][c], accL[qa]);

#pragma unroll
    for (int c = 0; c < 2; c++) {
      bf16x8_t va[4];
#pragma unroll
      for (int dm = 0; dm < 4; dm++) {
        const u16* vb = &Vs[kv][buf][(dm * 16 + r) * 64];
        union { uint4 u; bf16x8_t v; } cat;
        *(uint2*)&cat.u.x = *(const uint2*)(vb + vo0[c]);
        *(uint2*)&cat.u.z = *(const uint2*)(vb + vo1[c]);
        va[dm] = cat.v;
      }
      __builtin_amdgcn_s_setprio(1);
#pragma unroll
      for (int qa = 0; qa < 4; qa++)
#pragma unroll
        for (int dm = 0; dm < 4; dm++)
          accO[qa][dm] = mfma16(va[dm], pf[qa][c], accO[qa][dm]);
      __builtin_amdgcn_s_setprio(0);
    }
  }

  __syncthreads();
  float* Sc  = (float*)&Ks[0][0][0];
  float* Lsc = (float*)&Vs[0][0][0];
  if (kv == 1) {
#pragma unroll
    for (int qa = 0; qa < 4; qa++) {
#pragma unroll
      for (int dm = 0; dm < 4; dm++)
        *(f32x4_t*)&Sc[g * 4096 + ((qa * 4 + dm) * 64 + lane) * 4] = accO[qa][dm];
      Lsc[g * 256 + qa * 64 + lane] = accL[qa][0];
    }
  }
  __syncthreads();
  if (kv == 0) {
#pragma unroll
    for (int qa = 0; qa < 4; qa++) {
      float L = accL[qa][0] + Lsc[g * 256 + qa * 64 + lane];
      float inv = 1.f / L;
      int gq = q0 + g * 64 + qa * 16 + r;
#pragma unroll
      for (int dm = 0; dm < 4; dm++) {
        f32x4_t o = *(const f32x4_t*)&Sc[g * 4096 + ((qa * 4 + dm) * 64 + lane) * 4];
        o += accO[qa][dm];
        bf16x4_t ob;
#pragma unroll
        for (int reg = 0; reg < 4; reg++) ob[reg] = (__bf16)(o[reg] * inv);
        *(uint2*)&Oattn[bbase + (long)gq * 512 + h * 64 + dm * 16 + qd * 4] = *(uint2*)&ob;
      }
    }
  }
}

// ---------------- launch ----------------
extern "C" void kernel_launch(void* const* d_in, const int* in_sizes, int n_in,
                              void* d_out, int out_size, void* d_ws, size_t ws_size,
                              hipStream_t stream) {
  const float* x  = (const float*)d_in[0];
  const float* Wq = (const float*)d_in[1];
  const float* Wk = (const float*)d_in[2];
  const float* Wv = (const float*)d_in[3];
  const float* Wo = (const float*)d_in[4];
  const float* bo = (const float*)d_in[5];
  float* out = (float*)d_out;

  u16* ws  = (u16*)d_ws;
  u16* Qb  = ws;
  u16* Kb  = Qb  + 4194304;
  u16* Vtg = Kb  + 4194304;   // V^T: [2*512][4096]
  u16* Ab  = Vtg + 4194304;
  u16* Xb  = Ab;              // aliased: Xb live [cast, qkv); Ab live [attn, out) — disjoint
  u16* Wqb = Ab  + 4194304;
  u16* Wkb = Wqb + 262144;
  u16* Wvb = Wkb + 262144;
  u16* Wob = Wvb + 262144;

  cast_kernel<<<2560, 256, 0, stream>>>(x, Wq, Wk, Wv, Wo, Xb, Wqb, Wkb, Wvb, Wob);

  dim3 g1(64, 4, 3);
  gemm_qkv_kernel<<<g1, 256, 0, stream>>>(Xb, Wqb, Wkb, Wvb, Qb, Kb, Vtg);

  dim3 g2(32, 16);
  attn_kernel<<<g2, 256, 0, stream>>>(Qb, Kb, Vtg, Ab);

  dim3 g3(64, 4);
  gemm_out_kernel<<<g3, 256, 0, stream>>>(Ab, Wob, out, bo);
}